// Round 7
// baseline (115.400 us; speedup 1.0000x reference)
//
#include <hip/hip_runtime.h>

#define N 4096
#define F 512
#define FP 64
#define K 8
#define KFP 512          // K*FP
#define LOG2E 1.44269504088896f

#define BI 64            // attn: i-rows per block
#define BJ 128           // attn: j-cols staged per tile (16KB/buf -> 3 blocks/CU)
#define NTILE (N / BJ)   // 32

typedef __attribute__((ext_vector_type(8))) short short8;
typedef __attribute__((ext_vector_type(4))) float f32x4;
typedef __attribute__((ext_vector_type(2))) float f32x2;

__device__ __forceinline__ unsigned short f2bs(float x) {
  union { __bf16 b; unsigned short u; } u;
  u.b = (__bf16)x;
  return u.u;
}

#if __has_builtin(__builtin_amdgcn_exp2f)
#define EXP2(x) __builtin_amdgcn_exp2f(x)
#else
#define EXP2(x) __expf((x) * 0.6931471805599453f)
#endif

__device__ __forceinline__ f32x2 pk_add(f32x2 a, f32x2 b) {
  f32x2 d;
  asm("v_pk_add_f32 %0, %1, %2" : "=v"(d) : "v"(a), "v"(b));
  return d;
}
__device__ __forceinline__ f32x2 pk_mul(f32x2 a, f32x2 b) {
  f32x2 d;
  asm("v_pk_mul_f32 %0, %1, %2" : "=v"(d) : "v"(a), "v"(b));
  return d;
}

// masked = bit(off) of mb ? w : 0.0f   (sbfe-sext + and)
__device__ __forceinline__ float mask_w(float w, unsigned mb, int off) {
  return __int_as_float(__float_as_int(w) & __builtin_amdgcn_sbfe((int)mb, off, 1));
}

// ---------------- prep: Xb = bf16(X), Wt = bf16(W transposed) ----------------------------
__global__ __launch_bounds__(256) void prep_fused(const float* __restrict__ X,
                                                  unsigned short* __restrict__ Xb,
                                                  const float* __restrict__ W,
                                                  unsigned short* __restrict__ Wt) {
  __shared__ unsigned short WT16[64][66];
  const int t = threadIdx.x;
  if (blockIdx.x < 1024) {                  // X -> Xb, 8 elems/thread
    const int idx = (blockIdx.x * 256 + t) * 8;
    const float4 v0 = *reinterpret_cast<const float4*>(&X[idx]);
    const float4 v1 = *reinterpret_cast<const float4*>(&X[idx + 4]);
    unsigned short o[8] = {f2bs(v0.x), f2bs(v0.y), f2bs(v0.z), f2bs(v0.w),
                           f2bs(v1.x), f2bs(v1.y), f2bs(v1.z), f2bs(v1.w)};
    *reinterpret_cast<uint4*>(&Xb[idx]) = *reinterpret_cast<uint4*>(&o[0]);
    return;
  }
  const int bid = blockIdx.x - 1024;        // W[K][F][FP] -> Wt[K*FP][F]
  const int k = bid >> 3;
  const int f0 = (bid & 7) * 64;
#pragma unroll
  for (int j = 0; j < 16; j++) {
    const int idx = j * 256 + t;
    const int fl = idx >> 6, p = idx & 63;
    WT16[p][fl] = f2bs(W[(k * F + f0 + fl) * FP + p]);
  }
  __syncthreads();
  const int p = t >> 2, uc = t & 3;
  unsigned short tmp[16];
#pragma unroll
  for (int j = 0; j < 16; j++) tmp[j] = WT16[p][uc * 16 + j];
  unsigned short* dst = &Wt[(k * 64 + p) * F + f0 + uc * 16];
  *reinterpret_cast<uint4*>(dst)     = *reinterpret_cast<uint4*>(&tmp[0]);
  *reinterpret_cast<uint4*>(dst + 8) = *reinterpret_cast<uint4*>(&tmp[8]);
}

// ---------------- kernel A: h_bT = Wt·Xb^T via MFMA + fused f1/f2 + fused adj bits -------
__global__ __launch_bounds__(256, 2) void gemm_h(
    const unsigned short* __restrict__ Xb, const unsigned short* __restrict__ Wt,
    const float* __restrict__ a, unsigned short* __restrict__ h_bT,
    float* __restrict__ f1, float* __restrict__ f2,
    const int* __restrict__ adj, unsigned long long* __restrict__ adjb) {
  __shared__ __align__(16) unsigned char AT[2][8192];   // Wt tile [64c][8u][16B]
  __shared__ __align__(16) unsigned char BT[2][8192];   // Xb tile [64n][8u][16B]
  __shared__ float F1L[2][64], F2L[2][64];

  const int t = threadIdx.x;
  const int k = blockIdx.x & 7;
  const int n0 = (blockIdx.x >> 3) * 64;
  const int wave = t >> 6, lane = t & 63;
  const int cg = wave >> 1, ng = wave & 1;
  const int col = lane & 15, kg = lane >> 4;
  const unsigned short* __restrict__ Wk = Wt + (size_t)k * 64 * F;

  f32x4 acc[2][2];
#pragma unroll
  for (int i = 0; i < 2; i++)
#pragma unroll
    for (int j = 0; j < 2; j++) acc[i][j] = (f32x4){0.f, 0.f, 0.f, 0.f};

  auto stage = [&](int tt, int buf) {
    const int f0 = tt * 64;
#pragma unroll
    for (int m = 0; m < 2; m++) {
      const int g = wave * 128 + m * 64 + lane;
      const int row = g >> 3, pu = g & 7;
      const int u = pu ^ (row & 7);
      const void* srcA = Wk + (size_t)row * F + f0 + u * 8;
      void* dstA = (void*)(AT[buf] + (wave * 128 + m * 64) * 16);
      __builtin_amdgcn_global_load_lds(
          (const __attribute__((address_space(1))) void*)srcA,
          (__attribute__((address_space(3))) void*)dstA, 16, 0, 0);
      const void* srcB = Xb + (size_t)(n0 + row) * F + f0 + u * 8;
      void* dstB = (void*)(BT[buf] + (wave * 128 + m * 64) * 16);
      __builtin_amdgcn_global_load_lds(
          (const __attribute__((address_space(1))) void*)srcB,
          (__attribute__((address_space(3))) void*)dstB, 16, 0, 0);
    }
  };

  auto compute = [&](int buf) {
#pragma unroll
    for (int ks = 0; ks < 2; ks++) {
      const int u0 = ks * 4 + kg;
      short8 af[2], bf[2];
#pragma unroll
      for (int i = 0; i < 2; i++) {
        const int rowA = cg * 32 + i * 16 + col;
        af[i] = *reinterpret_cast<const short8*>(
            AT[buf] + (rowA * 8 + (u0 ^ (rowA & 7))) * 16);
        const int rowB = ng * 32 + i * 16 + col;
        bf[i] = *reinterpret_cast<const short8*>(
            BT[buf] + (rowB * 8 + (u0 ^ (rowB & 7))) * 16);
      }
#pragma unroll
      for (int i = 0; i < 2; i++)
#pragma unroll
        for (int j = 0; j < 2; j++)
          acc[i][j] = __builtin_amdgcn_mfma_f32_16x16x32_bf16(af[i], bf[j], acc[i][j], 0, 0, 0);
    }
  };

  // fused adjacency: block owns 512 adjb words; wave owns 128; 16 per K-tile.
  int adjv[16];
  const int wb_wave = blockIdx.x * 512 + wave * 128;
  auto adj_load = [&](int c) {
    const int* p = adj + (size_t)(wb_wave + c * 16) * 64 + lane;
#pragma unroll
    for (int x = 0; x < 16; x++) adjv[x] = p[x * 64];
  };
  auto adj_process = [&](int c) {
    unsigned long long ms[16];
#pragma unroll
    for (int x = 0; x < 16; x++) ms[x] = __ballot(adjv[x] > 0);
    if (lane == 0) {
#pragma unroll
      for (int x = 0; x < 16; x++) adjb[wb_wave + c * 16 + x] = ms[x];
    }
  };

  stage(0, 0);
  adj_load(0);
  for (int tt = 0; tt < F / 64; ++tt) {
    const int cur = tt & 1;
    __builtin_amdgcn_s_barrier();
    __builtin_amdgcn_sched_barrier(0);
    if (tt + 1 < F / 64) {
      stage(tt + 1, 1 - cur);
      asm volatile("s_waitcnt vmcnt(4)" ::: "memory");
    } else {
      asm volatile("s_waitcnt vmcnt(0)" ::: "memory");
    }
    __builtin_amdgcn_s_barrier();
    __builtin_amdgcn_sched_barrier(0);
    if (tt >= 1) {
      adj_process(tt - 1);
      adj_load(tt);
    }
    compute(cur);
  }
  asm volatile("s_waitcnt vmcnt(0)" ::: "memory");
  adj_process(7);

  // ---- epilogue: h_bT bf16 stores + fused f1/f2 (pre-scaled by log2e) ----
  float p1[2] = {0.f, 0.f}, p2[2] = {0.f, 0.f};
#pragma unroll
  for (int i = 0; i < 2; i++) {
#pragma unroll
    for (int r = 0; r < 4; r++) {
      const int p = cg * 32 + i * 16 + kg * 4 + r;
      const float as = a[k * 128 + p];
      const float ad = a[k * 128 + 64 + p];
#pragma unroll
      for (int j = 0; j < 2; j++) {
        const float v = acc[i][j][r];
        h_bT[(size_t)(k * 64 + p) * N + n0 + ng * 32 + j * 16 + col] = f2bs(v);
        p1[j] = fmaf(v, as, p1[j]);
        p2[j] = fmaf(v, ad, p2[j]);
      }
    }
  }
#pragma unroll
  for (int j = 0; j < 2; j++) {
    p1[j] += __shfl_xor(p1[j], 16); p1[j] += __shfl_xor(p1[j], 32);
    p2[j] += __shfl_xor(p2[j], 16); p2[j] += __shfl_xor(p2[j], 32);
    if (kg == 0) {
      F1L[cg][ng * 32 + j * 16 + col] = p1[j];
      F2L[cg][ng * 32 + j * 16 + col] = p2[j];
    }
  }
  __syncthreads();
  if (t < 64) {
    f1[k * N + n0 + t] = (F1L[0][t] + F1L[1][t]) * LOG2E;
    f2[k * N + n0 + t] = (F2L[0][t] + F2L[1][t]) * LOG2E;
  }
}

// ---------------- kernel C: LDS-staged MFMA masked-softmax attention ---------------------
// block = (64 i-rows, head k). 8 waves = 2 i-groups x 4 j-quarters. BJ=128 -> 33KB LDS,
// 3 blocks/CU (launch_bounds 512,6): barrier stalls of one block hide under others.
__global__ __launch_bounds__(512, 6) void attn_mfma(
    const unsigned short* __restrict__ h_bT, const float* __restrict__ f1,
    const float* __restrict__ f2, const unsigned long long* __restrict__ adjb,
    float* __restrict__ out) {
  __shared__ __align__(16) unsigned char SMEM[32768];   // 2 x 16KB tile dbuf; CL at end
  __shared__ float DL[2][4][32];

  const int tid = threadIdx.x;
  const int k = blockIdx.x & 7;
  const int i0 = (blockIdx.x >> 3) * BI;
  const int wave = tid >> 6, lane = tid & 63;
  const int iq = wave >> 2;
  const int jq = wave & 3;
  const int col = lane & 15, kg = lane >> 4;

  const float* __restrict__ f1k = f1 + k * N;
  const unsigned char* __restrict__ hbb =
      (const unsigned char*)(h_bT + (size_t)k * 64 * N);

  const int rbase = i0 + iq * 32;
  const float f2r0 = f2[k * N + rbase + col];        // pre-scaled by log2e
  const float f2r1 = f2[k * N + rbase + 16 + col];
  const f32x2 f2r0_2 = {f2r0, f2r0};
  const f32x2 f2r1_2 = {f2r1, f2r1};
  const f32x2 c02 = {0.2f, 0.2f};
  // adjacency rows as 32-bit words: 128 words per row
  const unsigned* __restrict__ arow0 =
      (const unsigned*)(adjb + (size_t)(rbase + col) * 64);
  const unsigned* __restrict__ arow1 =
      (const unsigned*)(adjb + (size_t)(rbase + 16 + col) * 64);

  f32x4 acc[2][4];
  f32x4 accden[2];
#pragma unroll
  for (int a = 0; a < 2; a++) {
    accden[a] = (f32x4){0.f, 0.f, 0.f, 0.f};
#pragma unroll
    for (int n = 0; n < 4; n++) acc[a][n] = (f32x4){0.f, 0.f, 0.f, 0.f};
  }
  short8 bones;
#pragma unroll
  for (int e = 0; e < 8; e++) bones[e] = (short)0x3F80;

  // 16KB tile = 1024 x 16B units; row = unit>>4 (64 rows x 16 units), swizzle u^(row&15)
  auto stage = [&](int tt, int buf) {
#pragma unroll
    for (int m = 0; m < 2; m++) {
      const int g = wave * 128 + m * 64 + lane;
      const int row = g >> 4;
      const int pu = g & 15;
      const int u = pu ^ (row & 15);
      const void* src = hbb + (size_t)row * (N * 2) + tt * (BJ * 2) + u * 16;
      void* dst = (void*)(SMEM + buf * 16384 + (wave * 128 + m * 64) * 16);
      __builtin_amdgcn_global_load_lds(
          (const __attribute__((address_space(1))) void*)src,
          (__attribute__((address_space(3))) void*)dst, 16, 0, 0);
    }
  };

  auto compute_tile = [&](int tt, int buf) {
    const unsigned m0 = arow0[tt * 4 + jq];
    const unsigned m1 = arow1[tt * 4 + jq];
    const int jglob = tt * BJ + jq * 32 + kg * 8;
    const float4 fa = *reinterpret_cast<const float4*>(&f1k[jglob]);
    const float4 fb = *reinterpret_cast<const float4*>(&f1k[jglob + 4]);

    short8 bfrag[4];
#pragma unroll
    for (int n = 0; n < 4; n++) {
      const int row_b = n * 16 + col;
      const int u = jq * 4 + kg;
      const int pu = u ^ col;
      bfrag[n] = *reinterpret_cast<const short8*>(
          SMEM + buf * 16384 + row_b * 256 + pu * 16);
    }

    const f32x2 prs[4] = {{fa.x, fa.y}, {fa.z, fa.w}, {fb.x, fb.y}, {fb.z, fb.w}};
    union { unsigned u[4]; short8 s; } A0, A1;
#pragma unroll
    for (int e2 = 0; e2 < 4; e2++) {
      const f32x2 t0 = pk_add(prs[e2], f2r0_2);
      const f32x2 t1 = pk_add(prs[e2], f2r1_2);
      const f32x2 u0 = pk_mul(t0, c02);
      const f32x2 u1 = pk_mul(t1, c02);
      float w0a = EXP2(fmaxf(t0.x, u0.x));
      float w0b = EXP2(fmaxf(t0.y, u0.y));
      float w1a = EXP2(fmaxf(t1.x, u1.x));
      float w1b = EXP2(fmaxf(t1.y, u1.y));
      const int ob = kg * 8 + 2 * e2;
      w0a = mask_w(w0a, m0, ob);     w0b = mask_w(w0b, m0, ob + 1);
      w1a = mask_w(w1a, m1, ob);     w1b = mask_w(w1b, m1, ob + 1);
      asm("v_cvt_pk_bf16_f32 %0, %1, %2" : "=v"(A0.u[e2]) : "v"(w0a), "v"(w0b));
      asm("v_cvt_pk_bf16_f32 %0, %1, %2" : "=v"(A1.u[e2]) : "v"(w1a), "v"(w1b));
    }

    accden[0] = __builtin_amdgcn_mfma_f32_16x16x32_bf16(A0.s, bones, accden[0], 0, 0, 0);
    accden[1] = __builtin_amdgcn_mfma_f32_16x16x32_bf16(A1.s, bones, accden[1], 0, 0, 0);
#pragma unroll
    for (int n = 0; n < 4; n++) {
      acc[0][n] = __builtin_amdgcn_mfma_f32_16x16x32_bf16(A0.s, bfrag[n], acc[0][n], 0, 0, 0);
      acc[1][n] = __builtin_amdgcn_mfma_f32_16x16x32_bf16(A1.s, bfrag[n], acc[1][n], 0, 0, 0);
    }
  };

  stage(0, 0);
  for (int t = 0; t < NTILE; ++t) {
    const int cur = t & 1;
    __builtin_amdgcn_s_barrier();            // A: buf[1-cur] free to overwrite
    __builtin_amdgcn_sched_barrier(0);
    if (t + 1 < NTILE) {
      stage(t + 1, 1 - cur);
      // queue (old->new): stage(t)[2], stage(t+1)[2] -> keep 2 newest
      asm volatile("s_waitcnt vmcnt(2)" ::: "memory");
    } else {
      asm volatile("s_waitcnt vmcnt(0)" ::: "memory");
    }
    __builtin_amdgcn_s_barrier();            // B: buf[cur] staged for all waves
    __builtin_amdgcn_sched_barrier(0);
    compute_tile(t, cur);
  }
  __syncthreads();

  // ---- denominator exchange ----
  if (col == 0) {
#pragma unroll
    for (int a = 0; a < 2; a++)
#pragma unroll
      for (int r = 0; r < 4; r++) DL[iq][jq][a * 16 + kg * 4 + r] = accden[a][r];
  }
  __syncthreads();
  float rinv[2][4];
  if (jq == 0) {
#pragma unroll
    for (int a = 0; a < 2; a++)
#pragma unroll
      for (int r = 0; r < 4; r++) {
        const int il = a * 16 + kg * 4 + r;
        rinv[a][r] = 1.f / (DL[iq][0][il] + DL[iq][1][il] + DL[iq][2][il] + DL[iq][3][il]);
      }
  }

  // ---- cross-jq reduction in two 32-column passes (CL = 25KB, fits 32KB SMEM) ----
  float* CL = (float*)SMEM;   // [(iq*3+jqs)*32+row][33]
#pragma unroll
  for (int h = 0; h < 2; ++h) {
    if (jq != 0) {
#pragma unroll
      for (int a = 0; a < 2; a++)
#pragma unroll
        for (int nn = 0; nn < 2; nn++)
#pragma unroll
          for (int r = 0; r < 4; r++)
            CL[((iq * 3 + (jq - 1)) * 32 + a * 16 + kg * 4 + r) * 33 + nn * 16 + col] =
                acc[a][h * 2 + nn][r];
    }
    __syncthreads();
    if (jq == 0) {
#pragma unroll
      for (int a = 0; a < 2; a++)
#pragma unroll
        for (int r = 0; r < 4; r++) {
          const int il = a * 16 + kg * 4 + r;
#pragma unroll
          for (int nn = 0; nn < 2; nn++) {
            const int n = h * 2 + nn;
            float v = acc[a][n][r];
            v += CL[((iq * 3 + 0) * 32 + il) * 33 + nn * 16 + col];
            v += CL[((iq * 3 + 1) * 32 + il) * 33 + nn * 16 + col];
            v += CL[((iq * 3 + 2) * 32 + il) * 33 + nn * 16 + col];
            out[(size_t)(i0 + iq * 32 + il) * KFP + k * 64 + n * 16 + col] = v * rinv[a][r];
          }
        }
    }
    __syncthreads();
  }
}

// ---------------- launch ----------------------------------------------------------------
extern "C" void kernel_launch(void* const* d_in, const int* in_sizes, int n_in,
                              void* d_out, int out_size, void* d_ws, size_t ws_size,
                              hipStream_t stream) {
  const float* X   = (const float*)d_in[0];             // (N, F)
  const int*   adj = (const int*)d_in[1];               // (N, N)
  const float* W   = (const float*)d_in[2];             // (K, F, FP)
  const float* a   = (const float*)d_in[3];             // (K, 2*FP, 1)
  float* out = (float*)d_out;                           // (N, K*FP) = 8 MB

  char* ws = (char*)d_ws;
  unsigned short* h_bT = (unsigned short*)(ws);                    // 4 MB
  float* f1  = (float*)(ws + 4194304);                             // 128 KB
  float* f2  = (float*)(ws + 4325376);                             // 128 KB
  unsigned long long* adjb = (unsigned long long*)(ws + 4456448);  // 2 MB
  unsigned short* Wt = (unsigned short*)(ws + 6553600);            // 512 KB
  // Xb parked in d_out (4 MB of its 8 MB) — consumed by gemm_h before attn overwrites out
  unsigned short* Xb = (unsigned short*)d_out;

  hipLaunchKernelGGL(prep_fused, dim3(1024 + K * (F / 64)), dim3(256), 0, stream,
                     X, Xb, W, Wt);
  hipLaunchKernelGGL(gemm_h, dim3(K * (N / 64)), dim3(256), 0, stream,
                     Xb, Wt, a, h_bT, f1, f2, adj, adjb);
  hipLaunchKernelGGL(attn_mfma, dim3((N / BI) * K), dim3(512), 0, stream,
                     h_bT, f1, f2, adjb, out);
}

// Round 8
// 79.484 us; speedup vs baseline: 1.4519x; 1.4519x over previous
//
#include <hip/hip_runtime.h>

#define N 4096
#define F 512
#define FP 64
#define K 8
#define KFP 512          // K*FP
#define LOG2E 1.44269504088896f

#define BI 64            // attn: i-rows per block
#define BJ 256           // attn: j-cols staged per tile
#define NTILE (N / BJ)   // 16
#define SMH 65536        // bytes of h double-buffer in SMEM

typedef __attribute__((ext_vector_type(8))) short short8;
typedef __attribute__((ext_vector_type(4))) float f32x4;
typedef __attribute__((ext_vector_type(2))) float f32x2;

__device__ __forceinline__ unsigned short f2bs(float x) {
  union { __bf16 b; unsigned short u; } u;
  u.b = (__bf16)x;
  return u.u;
}

#if __has_builtin(__builtin_amdgcn_exp2f)
#define EXP2(x) __builtin_amdgcn_exp2f(x)
#else
#define EXP2(x) __expf((x) * 0.6931471805599453f)
#endif

__device__ __forceinline__ f32x2 pk_add(f32x2 a, f32x2 b) {
  f32x2 d;
  asm("v_pk_add_f32 %0, %1, %2" : "=v"(d) : "v"(a), "v"(b));
  return d;
}
__device__ __forceinline__ f32x2 pk_mul(f32x2 a, f32x2 b) {
  f32x2 d;
  asm("v_pk_mul_f32 %0, %1, %2" : "=v"(d) : "v"(a), "v"(b));
  return d;
}

// masked = bit(off) of mb ? w : 0.0f   (sbfe-sext + and)
__device__ __forceinline__ float mask_w(float w, unsigned mb, int off) {
  return __int_as_float(__float_as_int(w) & __builtin_amdgcn_sbfe((int)mb, off, 1));
}

#define GLOAD_LDS(src, dst) \
  __builtin_amdgcn_global_load_lds( \
      (const __attribute__((address_space(1))) void*)(src), \
      (__attribute__((address_space(3))) void*)(dst), 16, 0, 0)

// ---------------- prep: Xb = bf16(X), Wt = bf16(W transposed) ----------------------------
__global__ __launch_bounds__(256) void prep_fused(const float* __restrict__ X,
                                                  unsigned short* __restrict__ Xb,
                                                  const float* __restrict__ W,
                                                  unsigned short* __restrict__ Wt) {
  __shared__ unsigned short WT16[64][66];
  const int t = threadIdx.x;
  if (blockIdx.x < 1024) {                  // X -> Xb, 8 elems/thread
    const int idx = (blockIdx.x * 256 + t) * 8;
    const float4 v0 = *reinterpret_cast<const float4*>(&X[idx]);
    const float4 v1 = *reinterpret_cast<const float4*>(&X[idx + 4]);
    unsigned short o[8] = {f2bs(v0.x), f2bs(v0.y), f2bs(v0.z), f2bs(v0.w),
                           f2bs(v1.x), f2bs(v1.y), f2bs(v1.z), f2bs(v1.w)};
    *reinterpret_cast<uint4*>(&Xb[idx]) = *reinterpret_cast<uint4*>(&o[0]);
    return;
  }
  const int bid = blockIdx.x - 1024;        // W[K][F][FP] -> Wt[K*FP][F]
  const int k = bid >> 3;
  const int f0 = (bid & 7) * 64;
#pragma unroll
  for (int j = 0; j < 16; j++) {
    const int idx = j * 256 + t;
    const int fl = idx >> 6, p = idx & 63;
    WT16[p][fl] = f2bs(W[(k * F + f0 + fl) * FP + p]);
  }
  __syncthreads();
  const int p = t >> 2, uc = t & 3;
  unsigned short tmp[16];
#pragma unroll
  for (int j = 0; j < 16; j++) tmp[j] = WT16[p][uc * 16 + j];
  unsigned short* dst = &Wt[(k * 64 + p) * F + f0 + uc * 16];
  *reinterpret_cast<uint4*>(dst)     = *reinterpret_cast<uint4*>(&tmp[0]);
  *reinterpret_cast<uint4*>(dst + 8) = *reinterpret_cast<uint4*>(&tmp[8]);
}

// ---------------- kernel A: h_bT = Wt·Xb^T via MFMA + fused f1/f2 + fused adj bits -------
__global__ __launch_bounds__(256, 2) void gemm_h(
    const unsigned short* __restrict__ Xb, const unsigned short* __restrict__ Wt,
    const float* __restrict__ a, unsigned short* __restrict__ h_bT,
    float* __restrict__ f1, float* __restrict__ f2,
    const int* __restrict__ adj, unsigned long long* __restrict__ adjb) {
  __shared__ __align__(16) unsigned char AT[2][8192];   // Wt tile [64c][8u][16B]
  __shared__ __align__(16) unsigned char BT[2][8192];   // Xb tile [64n][8u][16B]
  __shared__ float F1L[2][64], F2L[2][64];

  const int t = threadIdx.x;
  const int k = blockIdx.x & 7;
  const int n0 = (blockIdx.x >> 3) * 64;
  const int wave = t >> 6, lane = t & 63;
  const int cg = wave >> 1, ng = wave & 1;
  const int col = lane & 15, kg = lane >> 4;
  const unsigned short* __restrict__ Wk = Wt + (size_t)k * 64 * F;

  f32x4 acc[2][2];
#pragma unroll
  for (int i = 0; i < 2; i++)
#pragma unroll
    for (int j = 0; j < 2; j++) acc[i][j] = (f32x4){0.f, 0.f, 0.f, 0.f};

  auto stage = [&](int tt, int buf) {
    const int f0 = tt * 64;
#pragma unroll
    for (int m = 0; m < 2; m++) {
      const int g = wave * 128 + m * 64 + lane;
      const int row = g >> 3, pu = g & 7;
      const int u = pu ^ (row & 7);
      GLOAD_LDS(Wk + (size_t)row * F + f0 + u * 8,
                AT[buf] + (wave * 128 + m * 64) * 16);
      GLOAD_LDS(Xb + (size_t)(n0 + row) * F + f0 + u * 8,
                BT[buf] + (wave * 128 + m * 64) * 16);
    }
  };

  auto compute = [&](int buf) {
#pragma unroll
    for (int ks = 0; ks < 2; ks++) {
      const int u0 = ks * 4 + kg;
      short8 af[2], bf[2];
#pragma unroll
      for (int i = 0; i < 2; i++) {
        const int rowA = cg * 32 + i * 16 + col;
        af[i] = *reinterpret_cast<const short8*>(
            AT[buf] + (rowA * 8 + (u0 ^ (rowA & 7))) * 16);
        const int rowB = ng * 32 + i * 16 + col;
        bf[i] = *reinterpret_cast<const short8*>(
            BT[buf] + (rowB * 8 + (u0 ^ (rowB & 7))) * 16);
      }
#pragma unroll
      for (int i = 0; i < 2; i++)
#pragma unroll
        for (int j = 0; j < 2; j++)
          acc[i][j] = __builtin_amdgcn_mfma_f32_16x16x32_bf16(af[i], bf[j], acc[i][j], 0, 0, 0);
    }
  };

  // fused adjacency: block owns 512 adjb words; wave owns 128; 16 per K-tile.
  int adjv[16];
  const int wb_wave = blockIdx.x * 512 + wave * 128;
  auto adj_load = [&](int c) {
    const int* p = adj + (size_t)(wb_wave + c * 16) * 64 + lane;
#pragma unroll
    for (int x = 0; x < 16; x++) adjv[x] = p[x * 64];
  };
  auto adj_process = [&](int c) {
    unsigned long long ms[16];
#pragma unroll
    for (int x = 0; x < 16; x++) ms[x] = __ballot(adjv[x] > 0);
    if (lane == 0) {
#pragma unroll
      for (int x = 0; x < 16; x++) adjb[wb_wave + c * 16 + x] = ms[x];
    }
  };

  stage(0, 0);
  adj_load(0);
  for (int tt = 0; tt < F / 64; ++tt) {
    const int cur = tt & 1;
    __builtin_amdgcn_s_barrier();
    __builtin_amdgcn_sched_barrier(0);
    if (tt + 1 < F / 64) {
      stage(tt + 1, 1 - cur);
      asm volatile("s_waitcnt vmcnt(4)" ::: "memory");
    } else {
      asm volatile("s_waitcnt vmcnt(0)" ::: "memory");
    }
    __builtin_amdgcn_s_barrier();
    __builtin_amdgcn_sched_barrier(0);
    if (tt >= 1) {
      adj_process(tt - 1);
      adj_load(tt);
    }
    compute(cur);
  }
  asm volatile("s_waitcnt vmcnt(0)" ::: "memory");
  adj_process(7);

  // ---- epilogue: h_bT bf16 stores + fused f1/f2 (pre-scaled by log2e) ----
  float p1[2] = {0.f, 0.f}, p2[2] = {0.f, 0.f};
#pragma unroll
  for (int i = 0; i < 2; i++) {
#pragma unroll
    for (int r = 0; r < 4; r++) {
      const int p = cg * 32 + i * 16 + kg * 4 + r;
      const float as = a[k * 128 + p];
      const float ad = a[k * 128 + 64 + p];
#pragma unroll
      for (int j = 0; j < 2; j++) {
        const float v = acc[i][j][r];
        h_bT[(size_t)(k * 64 + p) * N + n0 + ng * 32 + j * 16 + col] = f2bs(v);
        p1[j] = fmaf(v, as, p1[j]);
        p2[j] = fmaf(v, ad, p2[j]);
      }
    }
  }
#pragma unroll
  for (int j = 0; j < 2; j++) {
    p1[j] += __shfl_xor(p1[j], 16); p1[j] += __shfl_xor(p1[j], 32);
    p2[j] += __shfl_xor(p2[j], 16); p2[j] += __shfl_xor(p2[j], 32);
    if (kg == 0) {
      F1L[cg][ng * 32 + j * 16 + col] = p1[j];
      F2L[cg][ng * 32 + j * 16 + col] = p2[j];
    }
  }
  __syncthreads();
  if (t < 64) {
    f1[k * N + n0 + t] = (F1L[0][t] + F1L[1][t]) * LOG2E;
    f2[k * N + n0 + t] = (F2L[0][t] + F2L[1][t]) * LOG2E;
  }
}

// ---------------- kernel C: LDS-staged MFMA masked-softmax attention ---------------------
// block = (64 i-rows, head k). 8 waves = 2 i-groups x 4 j-quarters. BJ=256.
// h AND f1 AND adjb all staged via global_load_lds (no post-barrier global loads).
__global__ __launch_bounds__(512, 4) void attn_mfma(
    const unsigned short* __restrict__ h_bT, const float* __restrict__ f1,
    const float* __restrict__ f2, const unsigned long long* __restrict__ adjb,
    float* __restrict__ out) {
  // [0, 65536): h dbuf 2x32KB  |  [65536, 67584): f1 dbuf 2x1KB  |  [67584, 71680): adj dbuf 2x2KB
  __shared__ __align__(16) unsigned char SMEM[SMH + 2048 + 4096];
  __shared__ float DL[2][4][32];

  const int tid = threadIdx.x;
  const int k = blockIdx.x & 7;
  const int i0 = (blockIdx.x >> 3) * BI;
  const int wave = tid >> 6, lane = tid & 63;
  const int iq = wave >> 2;
  const int jq = wave & 3;
  const int col = lane & 15, kg = lane >> 4;

  const float* __restrict__ f1k = f1 + k * N;
  const unsigned char* __restrict__ hbb =
      (const unsigned char*)(h_bT + (size_t)k * 64 * N);

  const int rbase = i0 + iq * 32;
  const float f2r0 = f2[k * N + rbase + col];        // pre-scaled by log2e
  const float f2r1 = f2[k * N + rbase + 16 + col];
  const f32x2 f2r0_2 = {f2r0, f2r0};
  const f32x2 f2r1_2 = {f2r1, f2r1};
  const f32x2 c02 = {0.2f, 0.2f};

  f32x4 acc[2][4];
  f32x4 accden[2];
#pragma unroll
  for (int a = 0; a < 2; a++) {
    accden[a] = (f32x4){0.f, 0.f, 0.f, 0.f};
#pragma unroll
    for (int n = 0; n < 4; n++) acc[a][n] = (f32x4){0.f, 0.f, 0.f, 0.f};
  }
  short8 bones;
#pragma unroll
  for (int e = 0; e < 8; e++) bones[e] = (short)0x3F80;

  // stage h tile (all waves, 4 insts) + f1 tile (wave0, 1 inst) + adj tile (wave0, 2 insts)
  auto stage = [&](int tt, int buf) {
#pragma unroll
    for (int m = 0; m < 4; m++) {
      const int g = wave * 4 + m;
      const int row = g * 2 + (lane >> 5);
      const int pu = lane & 31;
      const int u = pu ^ (row & 15);
      GLOAD_LDS(hbb + (size_t)row * (N * 2) + tt * (BJ * 2) + u * 16,
                SMEM + buf * 32768 + g * 1024);
    }
    if (wave == 0) {
      // f1 tile: 256 floats = 64 lanes x 16B, one inst
      GLOAD_LDS(f1k + tt * BJ + lane * 4, SMEM + SMH + buf * 1024);
      // adj tile: 64 rows x 4 u64 words (tt*4..tt*4+3) = 2KB, two insts
#pragma unroll
      for (int m = 0; m < 2; m++) {
        const int g = m * 64 + lane;
        const int row = g >> 1, half = g & 1;
        GLOAD_LDS(adjb + (size_t)(i0 + row) * 64 + tt * 4 + half * 2,
                  SMEM + SMH + 2048 + buf * 2048 + m * 1024);
      }
    }
  };

  auto compute_tile = [&](int buf) {
    const unsigned long long* ADJ =
        (const unsigned long long*)(SMEM + SMH + 2048 + buf * 2048);
    const uint2 aw0 = *reinterpret_cast<const uint2*>(&ADJ[(iq * 32 + col) * 4 + jq]);
    const uint2 aw1 = *reinterpret_cast<const uint2*>(&ADJ[(iq * 32 + 16 + col) * 4 + jq]);
    const float* F1 = (const float*)(SMEM + SMH + buf * 1024);
#pragma unroll
    for (int ks = 0; ks < 2; ks++) {
      const int jl = jq * 64 + ks * 32 + kg * 8;
      const float4 fa = *reinterpret_cast<const float4*>(&F1[jl]);
      const float4 fb = *reinterpret_cast<const float4*>(&F1[jl + 4]);
      const unsigned m0 = ks ? aw0.y : aw0.x;
      const unsigned m1 = ks ? aw1.y : aw1.x;

      short8 bfrag[4];
#pragma unroll
      for (int n = 0; n < 4; n++) {
        const int row_b = n * 16 + col;
        const int u = jq * 8 + ks * 4 + kg;
        const int pu = u ^ col;
        bfrag[n] = *reinterpret_cast<const short8*>(
            SMEM + buf * 32768 + row_b * 512 + pu * 16);
      }

      const f32x2 prs[4] = {{fa.x, fa.y}, {fa.z, fa.w}, {fb.x, fb.y}, {fb.z, fb.w}};
      union { unsigned u[4]; short8 s; } A0, A1;
#pragma unroll
      for (int e2 = 0; e2 < 4; e2++) {
        const f32x2 t0 = pk_add(prs[e2], f2r0_2);
        const f32x2 t1 = pk_add(prs[e2], f2r1_2);
        const f32x2 u0 = pk_mul(t0, c02);
        const f32x2 u1 = pk_mul(t1, c02);
        float w0a = EXP2(fmaxf(t0.x, u0.x));
        float w0b = EXP2(fmaxf(t0.y, u0.y));
        float w1a = EXP2(fmaxf(t1.x, u1.x));
        float w1b = EXP2(fmaxf(t1.y, u1.y));
        const int ob = kg * 8 + 2 * e2;
        w0a = mask_w(w0a, m0, ob);     w0b = mask_w(w0b, m0, ob + 1);
        w1a = mask_w(w1a, m1, ob);     w1b = mask_w(w1b, m1, ob + 1);
        asm("v_cvt_pk_bf16_f32 %0, %1, %2" : "=v"(A0.u[e2]) : "v"(w0a), "v"(w0b));
        asm("v_cvt_pk_bf16_f32 %0, %1, %2" : "=v"(A1.u[e2]) : "v"(w1a), "v"(w1b));
      }

      __builtin_amdgcn_s_setprio(1);
      accden[0] = __builtin_amdgcn_mfma_f32_16x16x32_bf16(A0.s, bones, accden[0], 0, 0, 0);
      accden[1] = __builtin_amdgcn_mfma_f32_16x16x32_bf16(A1.s, bones, accden[1], 0, 0, 0);
#pragma unroll
      for (int n = 0; n < 4; n++) {
        acc[0][n] = __builtin_amdgcn_mfma_f32_16x16x32_bf16(A0.s, bfrag[n], acc[0][n], 0, 0, 0);
        acc[1][n] = __builtin_amdgcn_mfma_f32_16x16x32_bf16(A1.s, bfrag[n], acc[1][n], 0, 0, 0);
      }
      __builtin_amdgcn_s_setprio(0);
    }
  };

  stage(0, 0);
  for (int t = 0; t < NTILE; ++t) {
    const int cur = t & 1;
    __builtin_amdgcn_s_barrier();            // A: buf[1-cur] free to overwrite
    __builtin_amdgcn_sched_barrier(0);
    if (t + 1 < NTILE) {
      stage(t + 1, 1 - cur);
      // per-wave queues (old->new): wave0: s(t)[7], s(t+1)[7]; others: s(t)[4], s(t+1)[4]
      if (wave == 0) asm volatile("s_waitcnt vmcnt(7)" ::: "memory");
      else           asm volatile("s_waitcnt vmcnt(4)" ::: "memory");
    } else {
      asm volatile("s_waitcnt vmcnt(0)" ::: "memory");
    }
    __builtin_amdgcn_s_barrier();            // B: buf[cur] fully staged for all waves
    __builtin_amdgcn_sched_barrier(0);
    compute_tile(cur);
  }
  __syncthreads();

  // ---- cross-jq reduction (CL aliases h-SMEM region only) + normalize + store ----
  float* CL = (float*)SMEM;                  // 191*66*4 = 50.4KB < 64KB
  if (jq != 0) {
#pragma unroll
    for (int a = 0; a < 2; a++) {
#pragma unroll
      for (int n = 0; n < 4; n++)
#pragma unroll
        for (int r = 0; r < 4; r++)
          CL[((iq * 3 + (jq - 1)) * 32 + a * 16 + kg * 4 + r) * 66 + n * 16 + col] =
              acc[a][n][r];
      if (col == 0)
#pragma unroll
        for (int r = 0; r < 4; r++) DL[iq][jq][a * 16 + kg * 4 + r] = accden[a][r];
    }
  } else {
#pragma unroll
    for (int a = 0; a < 2; a++)
      if (col == 0)
#pragma unroll
        for (int r = 0; r < 4; r++) DL[iq][0][a * 16 + kg * 4 + r] = accden[a][r];
  }
  __syncthreads();
  if (jq == 0) {
#pragma unroll
    for (int a = 0; a < 2; a++) {
#pragma unroll
      for (int r = 0; r < 4; r++) {
        const int il = a * 16 + kg * 4 + r;
        const float den = DL[iq][0][il] + DL[iq][1][il] + DL[iq][2][il] + DL[iq][3][il];
        const float rinv = 1.f / den;
#pragma unroll
        for (int n = 0; n < 4; n++) {
          float v = acc[a][n][r];
          v += CL[((iq * 3 + 0) * 32 + il) * 66 + n * 16 + col];
          v += CL[((iq * 3 + 1) * 32 + il) * 66 + n * 16 + col];
          v += CL[((iq * 3 + 2) * 32 + il) * 66 + n * 16 + col];
          out[(size_t)(i0 + iq * 32 + il) * KFP + k * 64 + n * 16 + col] = v * rinv;
        }
      }
    }
  }
}

// ---------------- launch ----------------------------------------------------------------
extern "C" void kernel_launch(void* const* d_in, const int* in_sizes, int n_in,
                              void* d_out, int out_size, void* d_ws, size_t ws_size,
                              hipStream_t stream) {
  const float* X   = (const float*)d_in[0];             // (N, F)
  const int*   adj = (const int*)d_in[1];               // (N, N)
  const float* W   = (const float*)d_in[2];             // (K, F, FP)
  const float* a   = (const float*)d_in[3];             // (K, 2*FP, 1)
  float* out = (float*)d_out;                           // (N, K*FP) = 8 MB

  char* ws = (char*)d_ws;
  unsigned short* h_bT = (unsigned short*)(ws);                    // 4 MB
  float* f1  = (float*)(ws + 4194304);                             // 128 KB
  float* f2  = (float*)(ws + 4325376);                             // 128 KB
  unsigned long long* adjb = (unsigned long long*)(ws + 4456448);  // 2 MB
  unsigned short* Wt = (unsigned short*)(ws + 6553600);            // 512 KB
  // Xb parked in d_out (4 MB of its 8 MB) — consumed by gemm_h before attn overwrites out
  unsigned short* Xb = (unsigned short*)d_out;

  hipLaunchKernelGGL(prep_fused, dim3(1024 + K * (F / 64)), dim3(256), 0, stream,
                     X, Xb, W, Wt);
  hipLaunchKernelGGL(gemm_h, dim3(K * (N / 64)), dim3(256), 0, stream,
                     Xb, Wt, a, h_bT, f1, f2, adj, adjb);
  hipLaunchKernelGGL(attn_mfma, dim3((N / BI) * K), dim3(512), 0, stream,
                     h_bT, f1, f2, adjb, out);
}